// Round 1
// baseline (101.856 us; speedup 1.0000x reference)
//
#include <hip/hip_runtime.h>

#define NBOX 64
#define BLK  256
#define CHUNK 4096

__global__ __launch_bounds__(BLK) void level_loss_partial(
    const float* __restrict__ att0, const float* __restrict__ att1,
    const float* __restrict__ att2, const float* __restrict__ att3,
    const float* __restrict__ att4,
    const float* __restrict__ bboxs,
    const int* __restrict__ Hp, const int* __restrict__ Wp,
    float* __restrict__ partial, int B)
{
    __shared__ int4   sbox[NBOX];   // (y1, y2, x1, x2) integer raster bounds
    __shared__ int    s_nv;
    __shared__ int    s_hasvalid;
    __shared__ double sred[BLK];

    const int tid  = threadIdx.x;
    const int bid  = blockIdx.x;
    const int b    = bid >> 3;          // 8 block-slots per batch
    const int slot = bid & 7;
    const int lid   = (slot < 4) ? 0 : (slot - 3);   // level id 0..4
    const int chunk = (slot < 4) ? slot : 0;
    const int lw  = 7 - lid;            // log2(width)
    const int w   = 1 << lw;
    const int h   = w;
    const int npx = h * w;

    const float Hf = (float)(*Hp);
    const float Wf = (float)(*Wp);

    // ---- stage + compact boxes (wave 0 only: threads 0..63 == one full wave) ----
    if (tid < 64) {
        const float* bb = bboxs + ((size_t)b * NBOX + tid) * 5;
        const float x1 = bb[0], y1 = bb[1], x2 = bb[2], y2 = bb[3], lab = bb[4];
        const bool valid = (lab != -1.0f) && (x1 <= Wf) && (y1 <= Hf)
                        && (x2 <= Wf) && (y2 <= Hf);
        const float area = (x2 - x1) * (y2 - y1);
        const float base = (float)(32 << lid);
        const float min_a = base * base * 0.5f;                 // exact
        const double bd   = (double)base * 1.58;
        const float max_a = (float)(bd * bd * 2.0);             // f64 math -> f32, matches JAX promotion
        const bool lv = valid && (area >= min_a) && (area <= max_a);

        const float sx = (float)w / Wf;   // powers of two: exact
        const float sy = (float)h / Hf;
        const float ix1 = fmaxf(floorf(x1 * sx), 0.0f);
        const float iy1 = fmaxf(floorf(y1 * sy), 0.0f);
        const float ix2 = fminf(ceilf(x2 * sx) + 1.0f, (float)w);
        const float iy2 = fminf(ceilf(y2 * sy) + 1.0f, (float)h);

        const unsigned long long mlv    = __ballot(lv);
        const unsigned long long mvalid = __ballot(valid);
        const int lane = tid;                    // wave 0
        const int pos  = __popcll(mlv & ((1ull << lane) - 1ull));
        if (lv) sbox[pos] = make_int4((int)iy1, (int)iy2, (int)ix1, (int)ix2);
        if (lane == 0) { s_nv = (int)__popcll(mlv); s_hasvalid = (mvalid != 0ull) ? 1 : 0; }
    }
    __syncthreads();

    const float* att = (lid == 0) ? att0 : (lid == 1) ? att1
                     : (lid == 2) ? att2 : (lid == 3) ? att3 : att4;
    const float* attb = att + (size_t)b * npx;

    const int nv    = s_nv;
    const int start = chunk * CHUNK;
    const int end   = min(npx, start + CHUNK);

    const float lo = 1e-7f;
    const float hi = (float)(1.0 - 1e-7);   // 0.99999988079...f, matches jnp.clip upper bound

    double acc = 0.0;
    for (int p = start + tid; p < end; p += BLK) {
        const int y = p >> lw;
        const int x = p & (w - 1);
        const float a  = attb[p];
        const float pc = fminf(fmaxf(a, lo), hi);
        bool cov = false;
        for (int i = 0; i < nv; ++i) {
            const int4 bx = sbox[i];
            cov |= (y >= bx.x) & (y < bx.y) & (x >= bx.z) & (x < bx.w);
        }
        acc += cov ? (double)(-logf(pc)) : (double)(-log1pf(-pc));
    }

    // ---- block reduction (double) ----
    sred[tid] = acc;
    __syncthreads();
    for (int s = BLK / 2; s > 0; s >>= 1) {
        if (tid < s) sred[tid] += sred[tid + s];
        __syncthreads();
    }
    if (tid == 0) {
        const double wgt = s_hasvalid
            ? 1.0 / (5.0 * (double)B * (double)npx)
            : 0.0;
        partial[bid] = (float)(sred[0] * wgt);
    }
}

__global__ __launch_bounds__(256) void reduce_partials(
    const float* __restrict__ partial, int n, float* __restrict__ out)
{
    __shared__ double sred[256];
    const int tid = threadIdx.x;
    double a = 0.0;
    for (int i = tid; i < n; i += 256) a += (double)partial[i];
    sred[tid] = a;
    __syncthreads();
    for (int s = 128; s > 0; s >>= 1) {
        if (tid < s) sred[tid] += sred[tid + s];
        __syncthreads();
    }
    if (tid == 0) out[0] = (float)sred[0];
}

extern "C" void kernel_launch(void* const* d_in, const int* in_sizes, int n_in,
                              void* d_out, int out_size, void* d_ws, size_t ws_size,
                              hipStream_t stream) {
    const float* att0  = (const float*)d_in[0];
    const float* att1  = (const float*)d_in[1];
    const float* att2  = (const float*)d_in[2];
    const float* att3  = (const float*)d_in[3];
    const float* att4  = (const float*)d_in[4];
    const float* bboxs = (const float*)d_in[5];
    const int*   Hp    = (const int*)d_in[6];
    const int*   Wp    = (const int*)d_in[7];
    float* out = (float*)d_out;

    const int B = in_sizes[5] / (NBOX * 5);   // 32
    const int nblk = B * 8;                   // 256 blocks
    float* partial = (float*)d_ws;            // nblk floats

    level_loss_partial<<<nblk, BLK, 0, stream>>>(att0, att1, att2, att3, att4,
                                                 bboxs, Hp, Wp, partial, B);
    reduce_partials<<<1, 256, 0, stream>>>(partial, nblk, out);
}

// Round 2
// 76.592 us; speedup vs baseline: 1.3298x; 1.3298x over previous
//
#include <hip/hip_runtime.h>

#define NBOX 64
#define BLK  256

__device__ __forceinline__ unsigned long long range_mask(int x1, int x2, int base) {
    int lo = max(x1 - base, 0);
    int hi = min(x2 - base, 64);
    if (lo >= hi) return 0ull;
    unsigned long long m = (~0ull) >> (64 - (hi - lo));
    return m << lo;
}

__global__ __launch_bounds__(BLK) void level_loss_partial(
    const float* __restrict__ att0, const float* __restrict__ att1,
    const float* __restrict__ att2, const float* __restrict__ att3,
    const float* __restrict__ att4,
    const float* __restrict__ bboxs,
    const int* __restrict__ Hp, const int* __restrict__ Wp,
    float* __restrict__ partial, int B)
{
    __shared__ unsigned long long smask[64][2];  // per-row x-coverage bitmask
    __shared__ int    s_hasvalid;
    __shared__ double sred[BLK];

    const int tid  = threadIdx.x;
    const int bid  = blockIdx.x;
    const int b    = bid >> 3;          // 8 block-slots per batch
    const int slot = bid & 7;
    const int lid   = (slot < 4) ? 0 : (slot - 3);   // level id 0..4
    const int chunk = (slot < 4) ? slot : 0;
    const int lw  = 7 - lid;            // log2(width)
    const int w   = 1 << lw;
    const int npx = w << lw;
    const int start = chunk * 4096;
    const int end   = min(npx, start + 4096);
    const int r0    = start >> lw;              // first row of this chunk
    const int nrows = (end - start) >> lw;

    const float Hf = (float)(*Hp);
    const float Wf = (float)(*Wp);

    // ---- wave 0: zero masks, then rasterize boxes into row bitmasks ----
    if (tid < 64) {
        smask[tid][0] = 0ull;
        smask[tid][1] = 0ull;

        const float* bb = bboxs + ((size_t)b * NBOX + tid) * 5;
        const float x1 = bb[0], y1 = bb[1], x2 = bb[2], y2 = bb[3], lab = bb[4];
        const bool valid = (lab != -1.0f) && (x1 <= Wf) && (y1 <= Hf)
                        && (x2 <= Wf) && (y2 <= Hf);
        const float area = (x2 - x1) * (y2 - y1);
        const float base = (float)(32 << lid);
        const float min_a = base * base * 0.5f;                 // exact in f32
        const double bd   = (double)base * 1.58;
        const float max_a = (float)(bd * bd * 2.0);             // f64 -> f32, matches JAX promotion
        const bool lv = valid && (area >= min_a) && (area <= max_a);

        const unsigned long long mvalid = __ballot(valid);
        if (tid == 0) s_hasvalid = (mvalid != 0ull) ? 1 : 0;

        if (lv) {
            const float sx = (float)w / Wf;   // powers of two: exact
            const float sy = (float)w / Hf;
            const int ix1 = (int)fmaxf(floorf(x1 * sx), 0.0f);
            const int iy1 = (int)fmaxf(floorf(y1 * sy), 0.0f);
            const int ix2 = (int)fminf(ceilf(x2 * sx) + 1.0f, (float)w);
            const int iy2 = (int)fminf(ceilf(y2 * sy) + 1.0f, (float)w);
            const int ys = max(iy1, r0);
            const int ye = min(iy2, r0 + nrows);
            const unsigned long long m0 = range_mask(ix1, ix2, 0);
            const unsigned long long m1 = range_mask(ix1, ix2, 64);
            for (int y = ys; y < ye; ++y) {
                if (m0) atomicOr(&smask[y - r0][0], m0);
                if (m1) atomicOr(&smask[y - r0][1], m1);
            }
        }
    }
    __syncthreads();

    const float* att = (lid == 0) ? att0 : (lid == 1) ? att1
                     : (lid == 2) ? att2 : (lid == 3) ? att3 : att4;
    const float* attb = att + (size_t)b * npx;

    const float lo_c = 1e-7f;
    const float hi_c = (float)(1.0 - 1e-7);   // matches jnp.clip upper bound

    double acc = 0.0;
    // each iteration: one float4 (4 consecutive px, always within one row and
    // one 64-bit mask word since 4 | 64 and p0 is 4-aligned)
    for (int p0 = start + tid * 4; p0 < end; p0 += BLK * 4) {
        const float4 a = *reinterpret_cast<const float4*>(attb + p0);
        const int y  = p0 >> lw;
        const int x0 = p0 & (w - 1);
        const unsigned int bits =
            (unsigned int)(smask[y - r0][(x0 >> 6) & 1] >> (x0 & 63)) & 0xFu;
        const float v0 = fminf(fmaxf(a.x, lo_c), hi_c);
        const float v1 = fminf(fmaxf(a.y, lo_c), hi_c);
        const float v2 = fminf(fmaxf(a.z, lo_c), hi_c);
        const float v3 = fminf(fmaxf(a.w, lo_c), hi_c);
        acc += (bits & 1u) ? (double)(-logf(v0)) : (double)(-log1pf(-v0));
        acc += (bits & 2u) ? (double)(-logf(v1)) : (double)(-log1pf(-v1));
        acc += (bits & 4u) ? (double)(-logf(v2)) : (double)(-log1pf(-v2));
        acc += (bits & 8u) ? (double)(-logf(v3)) : (double)(-log1pf(-v3));
    }

    // ---- block reduction (double, deterministic) ----
    sred[tid] = acc;
    __syncthreads();
    for (int s = BLK / 2; s > 0; s >>= 1) {
        if (tid < s) sred[tid] += sred[tid + s];
        __syncthreads();
    }
    if (tid == 0) {
        const double wgt = s_hasvalid
            ? 1.0 / (5.0 * (double)B * (double)npx)
            : 0.0;
        partial[bid] = (float)(sred[0] * wgt);
    }
}

__global__ __launch_bounds__(256) void reduce_partials(
    const float* __restrict__ partial, int n, float* __restrict__ out)
{
    __shared__ double sred[256];
    const int tid = threadIdx.x;
    double a = 0.0;
    for (int i = tid; i < n; i += 256) a += (double)partial[i];
    sred[tid] = a;
    __syncthreads();
    for (int s = 128; s > 0; s >>= 1) {
        if (tid < s) sred[tid] += sred[tid + s];
        __syncthreads();
    }
    if (tid == 0) out[0] = (float)sred[0];
}

extern "C" void kernel_launch(void* const* d_in, const int* in_sizes, int n_in,
                              void* d_out, int out_size, void* d_ws, size_t ws_size,
                              hipStream_t stream) {
    const float* att0  = (const float*)d_in[0];
    const float* att1  = (const float*)d_in[1];
    const float* att2  = (const float*)d_in[2];
    const float* att3  = (const float*)d_in[3];
    const float* att4  = (const float*)d_in[4];
    const float* bboxs = (const float*)d_in[5];
    const int*   Hp    = (const int*)d_in[6];
    const int*   Wp    = (const int*)d_in[7];
    float* out = (float*)d_out;

    const int B = in_sizes[5] / (NBOX * 5);   // 32
    const int nblk = B * 8;                   // 256 blocks
    float* partial = (float*)d_ws;            // nblk floats

    level_loss_partial<<<nblk, BLK, 0, stream>>>(att0, att1, att2, att3, att4,
                                                 bboxs, Hp, Wp, partial, B);
    reduce_partials<<<1, 256, 0, stream>>>(partial, nblk, out);
}